// Round 8
// baseline (231.633 us; speedup 1.0000x reference)
//
#include <hip/hip_runtime.h>

// Pre-emphasis IIR: out[t] = y[t] + 0.85*out[t-1], shift SKIP=91, scale 32768,
// clip, astype(int16) (trunc toward zero); harness reads d_out as int32.
//
// R12 -> R13: R12 proved 9-deep load MLP (asm-volatile batch + drain) does
// NOT help -> latency theory moves to the compute dataflow: 8 chunks x
// ~7 serialized DS-latency hops (5-step shfl scan + carry shuffles), chunks
// coupled by the carry chain -> ~56 serial DS hops/wave, VALUBusy 9%.
// KEY ALGEBRA: the inter-chunk carry weight is c^256 = 0.85^256 ~ 8.6e-19
// (the kernel already drops c^128 ~ 9e-10), so carry_c ~= T_c = zero-state
// total of window c alone -> ALL chunks are independent. R13: 9 windows
// loaded up front, 9 scans run with their 5 shuffle steps INTERLEAVED
// (9 independent DS ops per dependency level), then 8 parallel broadcasts
// T_prev = shfl(t_prev,63), then outputs. Critical path ~7 DS levels vs ~56.

#define BLOCK   256
#define SKIP    91
#define COEF    0.85f
#define CHUNK_N 256                  // elements per wave chunk (64 lanes x 4)
#define CHUNKS  8                    // output chunks per wave
#define SEG     (CHUNKS * CHUNK_N)   // 2048 outputs per wave
#define WPB     (BLOCK / 64)         // 4 waves per block
#define TILE    (WPB * SEG)          // 8192 outputs per block

typedef int v4i __attribute__((ext_vector_type(4)));

__device__ __forceinline__ int cvt16(float v) {
    float s = v * 32768.f;
    s = fminf(fmaxf(s, -32768.f), 32767.f);   // fuses to v_med3_f32
    return (int)s;                            // trunc toward zero
}

__device__ __forceinline__ float4 ld_guard(const float* __restrict__ sig,
                                           long yb, long n) {
    float4 x;
    x.x = (yb + 0 >= 0 && yb + 0 < n) ? sig[yb + 0] : 0.f;
    x.y = (yb + 1 >= 0 && yb + 1 < n) ? sig[yb + 1] : 0.f;
    x.z = (yb + 2 >= 0 && yb + 2 < n) ? sig[yb + 2] : 0.f;
    x.w = (yb + 3 >= 0 && yb + 3 < n) ? sig[yb + 3] : 0.f;
    return x;
}

template <bool FAST>
__device__ __forceinline__ void run_seg(const float* __restrict__ sig,
                                        int* __restrict__ out,
                                        long segBase, long ln, int lane) {
    // scan-step multipliers c^(4*2^d) — compile-time constants.
    const float K1  = COEF * COEF * COEF * COEF;   // c^4
    const float K2  = K1 * K1;                      // c^8
    const float K4  = K2 * K2;                      // c^16
    const float K8  = K4 * K4;                      // c^32
    const float K16 = K8 * K8;                      // c^64
    const float KS[5] = {K1, K2, K4, K8, K16};      // (c^128 step dropped: 9e-10)
    const float C1 = COEF, C2 = COEF * COEF, C3 = C2 * COEF;
    // prev-lane carry weight c^(4*lane) (lane 0 -> 1.0)
    const float wq = exp2f((float)lane * (4.0f * -0.23446525109f)); // log2(0.85)

    // ---- Load 9 windows: chunks 0..7 (outputs) + index 8 = warm window.
    // Window c covers y[segBase+92+c*256, +256); warm covers y[segBase-164,+256)
    // whose last element is y[segBase+91] = the carry point for chunk 0.
    float4 x[9];
    if constexpr (FAST) {
        const float* base = sig + segBase + 4 * (long)lane;   // 16B-aligned
#pragma unroll
        for (int c = 0; c < 8; ++c)
            x[c] = *reinterpret_cast<const float4*>(base + (SKIP + 1) + c * CHUNK_N);
        x[8] = *reinterpret_cast<const float4*>(base - 164);
    } else {
#pragma unroll
        for (int c = 0; c < 8; ++c)
            x[c] = ld_guard(sig, segBase + (SKIP + 1) + (long)c * CHUNK_N
                                 + 4 * (long)lane, ln);
        x[8] = ld_guard(sig, segBase - 164 + 4 * (long)lane, ln);
    }

    // ---- Local 4-element chains (all 9 independent).
    float t[9], s0[8], s1[8], s2[8];
#pragma unroll
    for (int c = 0; c < 9; ++c) {
        float a0 = x[c].x;
        float a1 = fmaf(a0, COEF, x[c].y);
        float a2 = fmaf(a1, COEF, x[c].z);
        float a3 = fmaf(a2, COEF, x[c].w);
        if (c < 8) { s0[c] = a0; s1[c] = a1; s2[c] = a2; }
        t[c] = a3;
    }

    // ---- Wave scans, STEP-INTERLEAVED across all 9 chunks: each dependency
    // level issues 9 independent shfl_up -> DS pipe stays full; critical
    // path is 5 DS-latency levels total (was 5 per chunk, serially chained).
#pragma unroll
    for (int d = 0; d < 5; ++d) {
        const int sh = 1 << d;
        float u[9];
#pragma unroll
        for (int c = 0; c < 9; ++c) u[c] = __shfl_up(t[c], sh, 64);
#pragma unroll
        for (int c = 0; c < 9; ++c)
            t[c] = (lane >= sh) ? fmaf(u[c], KS[d], t[c]) : t[c];
    }

    // ---- Cross-chunk composition: carry for chunk c = total of window c-1
    // (warm for c=0). Chain weight c^256 ~ 8.6e-19 -> chunks independent.
    float tsh[8], Tp[8];
#pragma unroll
    for (int c = 0; c < 8; ++c) tsh[c] = __shfl_up(t[c], 1, 64);
#pragma unroll
    for (int c = 0; c < 8; ++c) Tp[c] = __shfl(t[c == 0 ? 8 : c - 1], 63, 64);

    // ---- Outputs. p = full-scan value at prev lane's elem3:
    //   p = shfl_up(t,1) + c^(4*lane) * T_prev   (lane 0: p = T_prev)
    const long oLim = ln - SKIP;
#pragma unroll
    for (int c = 0; c < 8; ++c) {
        float u = (lane == 0) ? 0.f : tsh[c];
        float p = fmaf(Tp[c], wq, u);
        v4i iv;                               // realigned by SKIP%4=3
        iv.x = cvt16(p);
        iv.y = cvt16(fmaf(p, C1, s0[c]));
        iv.z = cvt16(fmaf(p, C2, s1[c]));
        iv.w = cvt16(fmaf(p, C3, s2[c]));
        const long ob = segBase + (long)c * CHUNK_N + 4 * (long)lane;
        if constexpr (FAST) {
            *reinterpret_cast<v4i*>(out + ob) = iv;
        } else {
            if (ob + 0 >= oLim) iv.x = 0;     // zero-pad tail outputs
            if (ob + 1 >= oLim) iv.y = 0;
            if (ob + 2 >= oLim) iv.z = 0;
            if (ob + 3 >= oLim) iv.w = 0;
            if (ob + 0 < ln) out[ob + 0] = iv.x;
            if (ob + 1 < ln) out[ob + 1] = iv.y;
            if (ob + 2 < ln) out[ob + 2] = iv.z;
            if (ob + 3 < ln) out[ob + 3] = iv.w;
        }
    }
}

__global__ __launch_bounds__(BLOCK, 6) void preemph_kernel(
        const float* __restrict__ sig, int* __restrict__ out, int n) {
    const long ln   = n;
    const int  lane = threadIdx.x & 63;
    const long segBase = (long)blockIdx.x * TILE + (long)(threadIdx.x >> 6) * SEG;
    if (segBase >= ln) return;

    // fast iff: warm reads >= 0  AND  loads end <= n  AND  no output zeroing.
    const bool fast = (segBase >= 164) && (segBase + SEG + SKIP + 1 <= ln);
    if (fast) run_seg<true >(sig, out, segBase, ln, lane);
    else      run_seg<false>(sig, out, segBase, ln, lane);
}

extern "C" void kernel_launch(void* const* d_in, const int* in_sizes, int n_in,
                              void* d_out, int out_size, void* d_ws, size_t ws_size,
                              hipStream_t stream) {
    const float* sig = (const float*)d_in[0];
    int* out = (int*)d_out;
    int n = in_sizes[0];
    int grid = (int)(((long)n + TILE - 1) / TILE);
    preemph_kernel<<<grid, BLOCK, 0, stream>>>(sig, out, n);
}